// Round 2
// baseline (7251.863 us; speedup 1.0000x reference)
//
#include <hip/hip_runtime.h>
#include <math.h>

// DRL4TSP decode: B=512, F=2, N=128, H=256, 128 steps.
// One workgroup (512 thr) owns 2 batch elems; all 128 steps in-kernel.
// R2: (a) register-tiled attention (4n x 32h per thread, s-values in regs
//     across all steps, one cA b128 per 4 n) -> LDS pipe traffic /4;
//     (b) W_hh L2 stream split in two halves, each FUSED instruction-level
//     with an attention scan (double-buffered weight loads) so the ~19K cyc
//     L2 stream hides the attention VALU instead of serializing with it.

#define NB 512
#define NF 2
#define NN 128
#define NH 256
#define NH3 768

// ws layout (floats):
//   0     : Mgi[768] float2   (W_ih·Wdec, 2 cols interleaved)
//   1536  : cgi[768]          (W_ih·bdec + b_ih)
//   2304  : cA[256] float4    (2*A_s0, 2*A_s1, 2*A_d1, va)
//   3328  : a0[256]           (2*(Wa_s·bs + Wa_d·(20*Wd0+bd)))
//   3584  : cP[256] float4    (2*P_s0, 2*P_s1, vp, 0)
//   4608  : (dead: pb/PC0/PC1 from R1)
//   5376  : WaH[256*256]      (2*Wa[:,2H:3H] row-major)
//   70912 : cP2[256] float4   (2*PC0, 2*PC1, 2*pb, 0)
// x2 pre-scaling folds tanh(x)=1-2/(1+exp(2x)) exactly.

__device__ __forceinline__ float fast_rcp(float x) { return __builtin_amdgcn_rcpf(x); }
__device__ __forceinline__ float sigm(float x) { return fast_rcp(1.0f + __expf(-x)); }
__device__ __forceinline__ float tanh_e(float y) { return 1.0f - 2.0f * fast_rcp(1.0f + __expf(y)); }
__device__ __forceinline__ float tanh_raw(float x) { return tanh_e(2.0f * x); }

__global__ void precompute_kernel(const float* __restrict__ Ws, const float* __restrict__ bs,
                                  const float* __restrict__ Wd, const float* __restrict__ bd,
                                  const float* __restrict__ Wdec, const float* __restrict__ bdec,
                                  const float* __restrict__ W_ih, const float* __restrict__ b_ih,
                                  const float* __restrict__ Wa, const float* __restrict__ va,
                                  const float* __restrict__ Wp, const float* __restrict__ vp,
                                  float* __restrict__ ws)
{
    int tid = blockIdx.x * blockDim.x + threadIdx.x;
    if (tid < 768) {                              // Mgi
        int j = tid; const float* wr = &W_ih[j * NH];
        float m0 = 0.f, m1 = 0.f;
        for (int k = 0; k < NH; k++) { float w = wr[k]; m0 = fmaf(w, Wdec[2*k], m0); m1 = fmaf(w, Wdec[2*k+1], m1); }
        ws[2*j] = m0; ws[2*j+1] = m1;
    } else if (tid < 1536) {                      // cgi
        int j = tid - 768; const float* wr = &W_ih[j * NH];
        float c = b_ih[j];
        for (int k = 0; k < NH; k++) c = fmaf(wr[k], bdec[k], c);
        ws[1536 + j] = c;
    } else if (tid < 1792) {                      // cA (x2 scaled except va)
        int h = tid - 1536; const float* war = &Wa[h * NH3];
        float as0 = 0.f, as1 = 0.f, ad1 = 0.f;
        for (int k = 0; k < NH; k++) {
            float w = war[k];
            as0 = fmaf(w, Ws[2*k], as0); as1 = fmaf(w, Ws[2*k+1], as1);
            ad1 = fmaf(war[NH + k], Wd[2*k+1], ad1);
        }
        float4 v = make_float4(2.f*as0, 2.f*as1, 2.f*ad1, va[h]);
        ((float4*)(ws + 2304))[h] = v;
    } else if (tid < 2048) {                      // a0 (x2)
        int h = tid - 1792; const float* war = &Wa[h * NH3];
        float a = 0.f;
        for (int k = 0; k < NH; k++) {
            a = fmaf(war[k], bs[k], a);
            a = fmaf(war[NH + k], fmaf(20.0f, Wd[2*k], bd[k]), a);
        }
        ws[3328 + h] = 2.f * a;
    } else if (tid < 2304) {                      // cP (x2 scaled except vp)
        int h = tid - 2048; const float* wpr = &Wp[h * 2 * NH];
        float p0 = 0.f, p1 = 0.f;
        for (int k = 0; k < NH; k++) { float w = wpr[k]; p0 = fmaf(w, Ws[2*k], p0); p1 = fmaf(w, Ws[2*k+1], p1); }
        float4 v = make_float4(2.f*p0, 2.f*p1, vp[h], 0.f);
        ((float4*)(ws + 3584))[h] = v;
    } else if (tid < 2560) {                      // cP2: (2*PC0, 2*PC1, 2*pb)
        int h = tid - 2304;
        const float* wps = &Wp[h * 2 * NH];
        const float* wpc = wps + NH;
        float p0 = 0.f, p1 = 0.f, pb = 0.f;
        for (int k = 0; k < NH; k++) {
            p0 = fmaf(wpc[k], Ws[2*k], p0);
            p1 = fmaf(wpc[k], Ws[2*k+1], p1);
            pb = fmaf(wps[k] + wpc[k], bs[k], pb);
        }
        float4 v = make_float4(2.f*p0, 2.f*p1, 2.f*pb, 0.f);
        ((float4*)(ws + 70912))[h] = v;
    } else if (tid < 2560 + 65536) {              // WaH pack (x2)
        int m = tid - 2560; int i = m >> 8, j = m & 255;
        ws[5376 + m] = 2.f * Wa[i * NH3 + 2 * NH + j];
    }
}

__global__ void __launch_bounds__(512)
drl_main(const float* __restrict__ gstatic, const float* __restrict__ gdyn,
         const float* __restrict__ glast, const float* __restrict__ gWhh,
         const float* __restrict__ gbhh, const float* __restrict__ wsb,
         float* __restrict__ out)
{
    __shared__ float s0[2][NN], s1[2][NN], d1[2][NN];
    __shared__ float hs[2][NH];
    __shared__ float ghs[2][NH3];
    __shared__ float qp[2][NH];
    __shared__ float4 cA[NH];
    __shared__ float4 cP[NH];
    __shared__ float4 cP2[NH];
    __shared__ float2 Mgi[NH3];
    __shared__ float cgi[NH3], bhh[NH3];
    __shared__ float a0v[NH];
    __shared__ float spart[2][NN * 9];     // attention partials, +1 pad stride
    __shared__ float Sw[2][2];
    __shared__ int idxs[2];

    const int t = threadIdx.x;
    const int g = t >> 8;          // batch elem within block
    const int r = t & 255;
    const int b0 = blockIdx.x * 2;

    // ---- stage inputs + coefficients into LDS
    for (int i = t; i < 2 * NN; i += 512) {
        int gg = i >> 7, n = i & 127, b = b0 + gg;
        s0[gg][n] = gstatic[b * (NF * NN) + n];
        s1[gg][n] = gstatic[b * (NF * NN) + NN + n];
        d1[gg][n] = gdyn[b * (NF * NN) + NN + n];
    }
    for (int i = t; i < 2 * NH; i += 512) {
        int gg = i >> 8, j = i & 255;
        hs[gg][j] = glast[(b0 + gg) * NH + j];
    }
    for (int i = t; i < 1536; i += 512) ((float*)Mgi)[i] = wsb[i];
    for (int i = t; i < 768;  i += 512) cgi[i] = wsb[1536 + i];
    for (int i = t; i < 1024; i += 512) ((float*)cA)[i] = wsb[2304 + i];
    if (t < 256) a0v[t] = wsb[3328 + t];
    for (int i = t; i < 1024; i += 512) ((float*)cP)[i] = wsb[3584 + i];
    for (int i = t; i < 1024; i += 512) ((float*)cP2)[i] = wsb[70912 + i];
    for (int i = t; i < 768;  i += 512) bhh[i] = gbhh[i];
    if (t == 0) { idxs[0] = 0; idxs[1] = 0; }
    __syncthreads();

    const float* WaH = wsb + 5376;
    const int jb = t >> 2, kq = t & 3;     // GEMV tiling (fused phases)
    const int jb2 = t >> 1, kh = t & 1;    // qp GEMV tiling

    // attention tiling: thread owns n-set {n0..n0+3}, h-set {hg + 8*hl}
    const int ng = r >> 3, hg = r & 7;
    const int n0 = ng * 4;
    float sv0[4], sv1[4], dv[4];
    #pragma unroll
    for (int j = 0; j < 4; j++) {
        sv0[j] = s0[g][n0 + j]; sv1[j] = s1[g][n0 + j]; dv[j] = d1[g][n0 + j];
    }
    float cwsum = 0.f, vpsum = 0.f;
    #pragma unroll 8
    for (int hl = 0; hl < 32; hl++) {
        cwsum += cA[hg + 8 * hl].w;
        vpsum += cP[hg + 8 * hl].z;
    }

    // ---- initial gh = W_hh*last_hh + b_hh (full 768 rows)
    {
        float acc[12];
        #pragma unroll
        for (int i = 0; i < 12; i++) acc[i] = 0.f;
        const float* wb = gWhh + jb * NH + 4 * kq;
        #pragma unroll 2
        for (int c = 0; c < 16; c++) {
            float4 h0 = *(const float4*)&hs[0][16 * c + 4 * kq];
            float4 h1 = *(const float4*)&hs[1][16 * c + 4 * kq];
            #pragma unroll
            for (int p = 0; p < 6; p++) {
                float4 w = *(const float4*)(wb + p * 128 * NH + 16 * c);
                acc[2*p]   = fmaf(w.x,h0.x,fmaf(w.y,h0.y,fmaf(w.z,h0.z,fmaf(w.w,h0.w,acc[2*p]))));
                acc[2*p+1] = fmaf(w.x,h1.x,fmaf(w.y,h1.y,fmaf(w.z,h1.z,fmaf(w.w,h1.w,acc[2*p+1]))));
            }
        }
        #pragma unroll
        for (int p = 0; p < 6; p++) {
            float u0 = acc[2*p], u1 = acc[2*p+1];
            u0 += __shfl_xor(u0, 1); u0 += __shfl_xor(u0, 2);
            u1 += __shfl_xor(u1, 1); u1 += __shfl_xor(u1, 2);
            if (kq == 0) { int j = jb + 128 * p; ghs[0][j] = u0 + bhh[j]; ghs[1][j] = u1 + bhh[j]; }
        }
    }
    __syncthreads();

    for (int step = 0; step < NN; step++) {
        // ---- P2: GRU elementwise
        {
            int id = idxs[g];
            float svA = s0[g][id], svB = s1[g][id];
            float2 m0 = Mgi[r], m1 = Mgi[NH + r], m2 = Mgi[2 * NH + r];
            float ir  = fmaf(m0.x, svA, fmaf(m0.y, svB, cgi[r]));
            float iz  = fmaf(m1.x, svA, fmaf(m1.y, svB, cgi[NH + r]));
            float inn = fmaf(m2.x, svA, fmaf(m2.y, svB, cgi[2 * NH + r]));
            float rr = sigm(ir + ghs[g][r]);
            float zz = sigm(iz + ghs[g][NH + r]);
            float nv = tanh_raw(fmaf(rr, ghs[g][2 * NH + r], inn));
            float ho = hs[g][r];
            hs[g][r] = fmaf(zz, ho - nv, nv);
        }
        __syncthreads();
        // ---- B: qp = 2*Wa_h*h + a0  (256 rows x 2 batch, 512 thr)
        {
            float u0 = 0.f, u1 = 0.f;
            const float* wq = WaH + jb2 * NH + 4 * kh;
            #pragma unroll 4
            for (int ks = 0; ks < 32; ks++) {
                float4 w  = *(const float4*)(wq + ks * 8);
                float4 h0 = *(const float4*)&hs[0][ks * 8 + 4 * kh];
                float4 h1 = *(const float4*)&hs[1][ks * 8 + 4 * kh];
                u0 = fmaf(w.x,h0.x,fmaf(w.y,h0.y,fmaf(w.z,h0.z,fmaf(w.w,h0.w,u0))));
                u1 = fmaf(w.x,h1.x,fmaf(w.y,h1.y,fmaf(w.z,h1.z,fmaf(w.w,h1.w,u1))));
            }
            u0 += __shfl_xor(u0, 1);
            u1 += __shfl_xor(u1, 1);
            if (kh == 0) { qp[0][jb2] = u0 + a0v[jb2]; qp[1][jb2] = u1 + a0v[jb2]; }
        }
        __syncthreads();
        // ---- C: fused W_hh rows [0,384) GEMV  +  attention scan P4
        {
            float a6[6];
            #pragma unroll
            for (int i = 0; i < 6; i++) a6[i] = 0.f;
            float at4[4] = {cwsum, cwsum, cwsum, cwsum};
            const float* wb = gWhh + jb * NH + 4 * kq;
            float4 wreg[2][3];
            #pragma unroll
            for (int p = 0; p < 3; p++) wreg[0][p] = *(const float4*)(wb + p * 128 * NH);
            #pragma unroll
            for (int ks = 0; ks < 16; ks++) {
                if (ks < 15) {
                    #pragma unroll
                    for (int p = 0; p < 3; p++)
                        wreg[(ks+1)&1][p] = *(const float4*)(wb + p * 128 * NH + (ks+1) * 16);
                }
                // two attention h-iterations between load issue and use
                #pragma unroll
                for (int u = 0; u < 2; u++) {
                    int h = hg + 8 * (2 * ks + u);
                    float4 c4 = cA[h];
                    float qv = qp[g][h];
                    float m2 = -2.f * c4.w;
                    #pragma unroll
                    for (int j = 0; j < 4; j++) {
                        float x = fmaf(c4.x, sv0[j], fmaf(c4.y, sv1[j], fmaf(c4.z, dv[j], qv)));
                        float rr = fast_rcp(1.0f + __expf(x));
                        at4[j] = fmaf(m2, rr, at4[j]);
                    }
                }
                float4 h0 = *(const float4*)&hs[0][ks * 16 + 4 * kq];
                float4 h1 = *(const float4*)&hs[1][ks * 16 + 4 * kq];
                #pragma unroll
                for (int p = 0; p < 3; p++) {
                    float4 w = wreg[ks&1][p];
                    a6[2*p]   = fmaf(w.x,h0.x,fmaf(w.y,h0.y,fmaf(w.z,h0.z,fmaf(w.w,h0.w,a6[2*p]))));
                    a6[2*p+1] = fmaf(w.x,h1.x,fmaf(w.y,h1.y,fmaf(w.z,h1.z,fmaf(w.w,h1.w,a6[2*p+1]))));
                }
            }
            #pragma unroll
            for (int j = 0; j < 4; j++) spart[g][(n0 + j) * 9 + hg] = at4[j];
            #pragma unroll
            for (int p = 0; p < 3; p++) {
                float u0 = a6[2*p], u1 = a6[2*p+1];
                u0 += __shfl_xor(u0, 1); u0 += __shfl_xor(u0, 2);
                u1 += __shfl_xor(u1, 1); u1 += __shfl_xor(u1, 2);
                if (kq == 0) { int j = jb + 128 * p; ghs[0][j] = u0 + bhh[j]; ghs[1][j] = u1 + bhh[j]; }
            }
        }
        __syncthreads();
        // ---- P5: sum partials + softmax over n -> weighted sums S0w,S1w
        if (r < 64) {
            int l = r;
            float v0 = 0.f, v1 = 0.f;
            #pragma unroll
            for (int hq = 0; hq < 8; hq++) {
                v0 += spart[g][l * 9 + hq];
                v1 += spart[g][(l + 64) * 9 + hq];
            }
            float m = fmaxf(v0, v1);
            #pragma unroll
            for (int o = 32; o; o >>= 1) m = fmaxf(m, __shfl_xor(m, o));
            float e0 = __expf(v0 - m), e1 = __expf(v1 - m);
            float ss = e0 + e1;
            #pragma unroll
            for (int o = 32; o; o >>= 1) ss += __shfl_xor(ss, o);
            float rs = fast_rcp(ss);
            float w0 = e0 * rs, w1 = e1 * rs;
            float t0 = fmaf(w0, s0[g][l], w1 * s0[g][l + 64]);
            float t1 = fmaf(w0, s1[g][l], w1 * s1[g][l + 64]);
            #pragma unroll
            for (int o = 32; o; o >>= 1) { t0 += __shfl_xor(t0, o); t1 += __shfl_xor(t1, o); }
            if (l == 0) { Sw[g][0] = t0; Sw[g][1] = t1; }
        }
        __syncthreads();
        // ---- P7: fused W_hh rows [384,768) GEMV  +  pointer scan
        {
            float S0 = Sw[g][0], S1 = Sw[g][1];
            float a6[6];
            #pragma unroll
            for (int i = 0; i < 6; i++) a6[i] = 0.f;
            float at4[4] = {vpsum, vpsum, vpsum, vpsum};
            const float* wb = gWhh + (384 + jb) * NH + 4 * kq;
            float4 wreg[2][3];
            #pragma unroll
            for (int p = 0; p < 3; p++) wreg[0][p] = *(const float4*)(wb + p * 128 * NH);
            #pragma unroll
            for (int ks = 0; ks < 16; ks++) {
                if (ks < 15) {
                    #pragma unroll
                    for (int p = 0; p < 3; p++)
                        wreg[(ks+1)&1][p] = *(const float4*)(wb + p * 128 * NH + (ks+1) * 16);
                }
                #pragma unroll
                for (int u = 0; u < 2; u++) {
                    int h = hg + 8 * (2 * ks + u);
                    float4 c4 = cP[h];
                    float4 c2 = cP2[h];
                    float pc = fmaf(c2.x, S0, fmaf(c2.y, S1, c2.z));
                    float m2 = -2.f * c4.z;
                    #pragma unroll
                    for (int j = 0; j < 4; j++) {
                        float x = fmaf(c4.x, sv0[j], fmaf(c4.y, sv1[j], pc));
                        float rr = fast_rcp(1.0f + __expf(x));
                        at4[j] = fmaf(m2, rr, at4[j]);
                    }
                }
                float4 h0 = *(const float4*)&hs[0][ks * 16 + 4 * kq];
                float4 h1 = *(const float4*)&hs[1][ks * 16 + 4 * kq];
                #pragma unroll
                for (int p = 0; p < 3; p++) {
                    float4 w = wreg[ks&1][p];
                    a6[2*p]   = fmaf(w.x,h0.x,fmaf(w.y,h0.y,fmaf(w.z,h0.z,fmaf(w.w,h0.w,a6[2*p]))));
                    a6[2*p+1] = fmaf(w.x,h1.x,fmaf(w.y,h1.y,fmaf(w.z,h1.z,fmaf(w.w,h1.w,a6[2*p+1]))));
                }
            }
            #pragma unroll
            for (int j = 0; j < 4; j++) spart[g][(n0 + j) * 9 + hg] = at4[j];
            #pragma unroll
            for (int p = 0; p < 3; p++) {
                float u0 = a6[2*p], u1 = a6[2*p+1];
                u0 += __shfl_xor(u0, 1); u0 += __shfl_xor(u0, 2);
                u1 += __shfl_xor(u1, 1); u1 += __shfl_xor(u1, 2);
                if (kq == 0) { int j = 384 + jb + 128 * p; ghs[0][j] = u0 + bhh[j]; ghs[1][j] = u1 + bhh[j]; }
            }
        }
        __syncthreads();
        // ---- P8: sum partials + softmax + argmax (first-index tiebreak) + outputs
        if (r < 64) {
            int l = r;
            float v0 = 0.f, v1 = 0.f;
            #pragma unroll
            for (int hq = 0; hq < 8; hq++) {
                v0 += spart[g][l * 9 + hq];
                v1 += spart[g][(l + 64) * 9 + hq];
            }
            float bv = v0; int bi = l;
            if (v1 > v0) { bv = v1; bi = l + 64; }
            #pragma unroll
            for (int o = 32; o; o >>= 1) {
                float ov = __shfl_xor(bv, o); int oi = __shfl_xor(bi, o);
                if (ov > bv || (ov == bv && oi < bi)) { bv = ov; bi = oi; }
            }
            float e0 = __expf(v0 - bv), e1 = __expf(v1 - bv);
            float ss = e0 + e1;
            #pragma unroll
            for (int o = 32; o; o >>= 1) ss += __shfl_xor(ss, o);
            if (l == 0) {
                idxs[g] = bi;
                int b = b0 + g;
                out[b * NN + step] = (float)bi;
                out[NB * NN + b * NN + step] = -logf(ss);
            }
        }
        __syncthreads();
    }
}

extern "C" void kernel_launch(void* const* d_in, const int* in_sizes, int n_in,
                              void* d_out, int out_size, void* d_ws, size_t ws_size,
                              hipStream_t stream) {
    const float* gstatic = (const float*)d_in[0];
    const float* gdyn    = (const float*)d_in[1];
    const float* glast   = (const float*)d_in[2];
    const float* Ws      = (const float*)d_in[3];
    const float* bs      = (const float*)d_in[4];
    const float* Wd      = (const float*)d_in[5];
    const float* bd      = (const float*)d_in[6];
    const float* Wdec    = (const float*)d_in[7];
    const float* bdec    = (const float*)d_in[8];
    const float* W_ih    = (const float*)d_in[9];
    const float* W_hh    = (const float*)d_in[10];
    const float* b_ih    = (const float*)d_in[11];
    const float* b_hh    = (const float*)d_in[12];
    const float* Wa      = (const float*)d_in[13];
    const float* va      = (const float*)d_in[14];
    const float* Wp      = (const float*)d_in[15];
    const float* vp      = (const float*)d_in[16];
    float* outp = (float*)d_out;
    float* wsb  = (float*)d_ws;

    // 2560 coefficient dots + 65536 WaH pack = 68096 tasks
    precompute_kernel<<<267, 256, 0, stream>>>(Ws, bs, Wd, bd, Wdec, bdec,
                                               W_ih, b_ih, Wa, va, Wp, vp, wsb);
    drl_main<<<256, 512, 0, stream>>>(gstatic, gdyn, glast, W_hh, b_hh, wsb, outp);
}